// Round 10
// baseline (187.498 us; speedup 1.0000x reference)
//
#include <hip/hip_runtime.h>
#include <cmath>

#define NNODES 4096
#define FDIM 512
#define DH 64
#define CAP 128

// ---------------------------------------------------------------------------
// R9 NOTE: a fused-tail variant with a lightweight device-scope grid barrier
// produced stale data (absmax 0.78): coarse-grained device memory is NOT made
// visible cross-XCD by agent fences/atomics on gfx950 — only kernel
// boundaries (or cg::grid.sync's ~110us flush protocol) are. The 4-kernel
// structure below is therefore minimal: each mm->agg dependency is global
// (aggregation reads arbitrary nodes) and needs a kernel-boundary barrier.
// ---------------------------------------------------------------------------

// ---------------------------------------------------------------------------
// Kernel 1 (heterogeneous): blocks [0,1024) run layer-0 mm+proj; blocks
// [1024,1024+4096) build neighbor lists (one block per adjacency row).
// mm role: feat rows staged to LDS via coalesced float4 loads.
// build role: ballot-compaction — one LDS atomic per wave per round, empty
// rounds (~70%) skipped with a single uniform branch.
// ---------------------------------------------------------------------------
__global__ __launch_bounds__(256) void k_mm0_build(
    const float* __restrict__ adj, int* __restrict__ nbr, int* __restrict__ deg,
    const float* __restrict__ feat, const float* __restrict__ W0,
    const float* __restrict__ al0, const float* __restrict__ ar0,
    float* __restrict__ x, float* __restrict__ el, float* __restrict__ er)
{
    __shared__ float feat_s[4][FDIM];   // 8 KB (mm role)
    __shared__ float part[4][4][DH];    // 4 KB (mm role)
    __shared__ int cnt;                 // build role
    const int lane = threadIdx.x & 63;

    if (blockIdx.x >= NNODES / 4) {
        const int row = blockIdx.x - NNODES / 4;
        if (threadIdx.x == 0) cnt = 0;
        __syncthreads();
        const float4* arow = reinterpret_cast<const float4*>(adj + (size_t)row * NNODES);
        int* nrow = nbr + (size_t)row * CAP;
        float4 v[4];
        v[0] = arow[threadIdx.x];
        v[1] = arow[threadIdx.x + 256];
        v[2] = arow[threadIdx.x + 512];
        v[3] = arow[threadIdx.x + 768];
        const unsigned long long lmask = (1ull << lane) - 1ull;
#pragma unroll
        for (int s = 0; s < 4; s++) {
            const int colbase = (threadIdx.x + s * 256) * 4;
            float vals[4] = {v[s].x, v[s].y, v[s].z, v[s].w};
#pragma unroll
            for (int e = 0; e < 4; e++) {
                bool nz = vals[e] != 0.f;
                unsigned long long m = __ballot(nz);
                if (m) {
                    int base = 0;
                    if (lane == 0) base = atomicAdd(&cnt, __popcll(m));
                    base = __shfl(base, 0, 64);
                    if (nz) {
                        int idx = base + __popcll(m & lmask);
                        if (idx < CAP) nrow[idx] = colbase + e;
                    }
                }
            }
        }
        __syncthreads();
        if (threadIdx.x == 0) deg[row] = cnt < CAP ? cnt : CAP;
        return;
    }

    // ---- mm0+proj0: 4 nodes per block, wave = K-quarter, feat from LDS
    const int kq = threadIdx.x >> 6;
    const int r0 = blockIdx.x * 4;
    {
        const float4* fsrc = reinterpret_cast<const float4*>(feat + (size_t)r0 * FDIM);
        float4* fdst = reinterpret_cast<float4*>(&feat_s[0][0]);
        fdst[threadIdx.x] = fsrc[threadIdx.x];
        fdst[threadIdx.x + 256] = fsrc[threadIdx.x + 256];
    }
    __syncthreads();

    float acc[4] = {0.f, 0.f, 0.f, 0.f};
    const int k0 = kq * (FDIM / 4);
    for (int k = k0; k < k0 + FDIM / 4; k += 8) {
        float w[8];
#pragma unroll
        for (int u = 0; u < 8; u++) w[u] = W0[(k + u) * DH + lane];
#pragma unroll
        for (int r = 0; r < 4; r++) {
            float4 a0 = *reinterpret_cast<const float4*>(&feat_s[r][k]);
            float4 a1 = *reinterpret_cast<const float4*>(&feat_s[r][k + 4]);
            acc[r] = fmaf(a0.x, w[0], fmaf(a0.y, w[1], fmaf(a0.z, w[2], fmaf(a0.w, w[3], acc[r]))));
            acc[r] = fmaf(a1.x, w[4], fmaf(a1.y, w[5], fmaf(a1.z, w[6], fmaf(a1.w, w[7], acc[r]))));
        }
    }
    __syncthreads();
#pragma unroll
    for (int r = 0; r < 4; r++) part[kq][r][lane] = acc[r];
    __syncthreads();

    float xv = part[0][kq][lane] + part[1][kq][lane] + part[2][kq][lane] + part[3][kq][lane];
    const int node = r0 + kq;
    x[(size_t)node * DH + lane] = xv;
#pragma unroll
    for (int hh = 0; hh < 8; hh++) {
        float vl = xv * al0[lane * 8 + hh];
        float vr = xv * ar0[lane * 8 + hh];
#pragma unroll
        for (int off = 32; off >= 1; off >>= 1) {
            vl += __shfl_xor(vl, off, 64);
            vr += __shfl_xor(vr, off, 64);
        }
        if (lane == 0) {
            el[node * 8 + hh] = vl;
            er[node * 8 + hh] = vr;
        }
    }
}

// ---------------------------------------------------------------------------
// Kernel 2/3 (fused agg_L + mm_{L+1} + proj): block = 4 nodes, 256 threads.
// Phase A: ONE wave-task per node covering all 8 heads.
//   weight round: lane = (nbr 0..7) x (head 0..7), one expf per (j,h),
//     weights -> LDS tile, den accumulated per-lane, one xor-reduce/node.
//   aggregate round: 8 unrolled iters {shfl j, 2x broadcast ds_read_b128
//     (8 head weights), coalesced x load, 8 fma}. Padded lanes carry w=0.
// Phase B: x_out = h_s @ W from LDS (wave = K-quarter), then el/er proj.
// ---------------------------------------------------------------------------
template <int PROJ_H>
__global__ __launch_bounds__(256) void k_agg_mm(
    const float* __restrict__ x_in, const float* __restrict__ el_in,
    const float* __restrict__ er_in, const int* __restrict__ nbr,
    const int* __restrict__ deg, const float* __restrict__ bias_agg,
    const float* __restrict__ W, const float* __restrict__ al,
    const float* __restrict__ ar, float* __restrict__ x_out,
    float* __restrict__ el_out, float* __restrict__ er_out)
{
    __shared__ float h_s[4][FDIM];     // 8 KB
    __shared__ float part[4][4][DH];   // 4 KB
    __shared__ float w_s[4][8][8];     // 1 KB
    const int lane = threadIdx.x & 63;
    const int wv = threadIdx.x >> 6;   // 0..3 = node within block
    const int node = blockIdx.x * 4 + wv;
    const float bv = bias_agg[lane];

    // ---- Phase A: all 8 heads of one node per wave
    {
        const int nl = lane >> 3;      // neighbor slot 0..7
        const int hh = lane & 7;       // head 0..7
        const float eli = el_in[node * 8 + hh];
        float acc[8] = {0.f, 0.f, 0.f, 0.f, 0.f, 0.f, 0.f, 0.f};
        float denp = 0.f;
        const int dg = deg[node];
        const int* nb = nbr + (size_t)node * CAP;

        for (int c0 = 0; c0 < dg; c0 += 8) {
            // weight round: one expf per (neighbor, head)
            int jj = c0 + nl;
            int jidx = jj < dg ? jj : dg - 1;
            int j = nb[jidx];
            float e = er_in[j * 8 + hh];
            float s = eli + e;
            s = s > 0.f ? s : 0.2f * s;
            float w = (jj < dg) ? __expf(s) : 0.f;
            w_s[wv][nl][hh] = w;
            denp += w;
            // aggregate round: lane = feature dim
#pragma unroll
            for (int k = 0; k < 8; k++) {
                int jk = __shfl(j, k * 8, 64);
                float4 wa = *reinterpret_cast<const float4*>(&w_s[wv][k][0]);
                float4 wb = *reinterpret_cast<const float4*>(&w_s[wv][k][4]);
                float xv = x_in[(size_t)jk * DH + lane];
                acc[0] = fmaf(wa.x, xv, acc[0]);
                acc[1] = fmaf(wa.y, xv, acc[1]);
                acc[2] = fmaf(wa.z, xv, acc[2]);
                acc[3] = fmaf(wa.w, xv, acc[3]);
                acc[4] = fmaf(wb.x, xv, acc[4]);
                acc[5] = fmaf(wb.y, xv, acc[5]);
                acc[6] = fmaf(wb.z, xv, acc[6]);
                acc[7] = fmaf(wb.w, xv, acc[7]);
            }
        }
        // reduce den over neighbor-slot lanes (bits 3..5); lane h then holds den[h]
        denp += __shfl_xor(denp, 8, 64);
        denp += __shfl_xor(denp, 16, 64);
        denp += __shfl_xor(denp, 32, 64);
#pragma unroll
        for (int h = 0; h < 8; h++) {
            float den = __shfl(denp, h, 64);
            float o = acc[h] / fmaxf(den, 1e-12f) + bv;
            o = o > 0.f ? o : __expf(o) - 1.f;     // elu
            h_s[wv][h * DH + lane] = o;
        }
    }
    __syncthreads();

    // ---- Phase B: mm + proj from LDS (wave = K-quarter)
    float acc[4] = {0.f, 0.f, 0.f, 0.f};
    const int k0 = wv * (FDIM / 4);
    for (int k = k0; k < k0 + FDIM / 4; k += 8) {
        float w[8];
#pragma unroll
        for (int u = 0; u < 8; u++) w[u] = W[(k + u) * DH + lane];
#pragma unroll
        for (int r = 0; r < 4; r++) {
            float4 a0 = *reinterpret_cast<const float4*>(&h_s[r][k]);
            float4 a1 = *reinterpret_cast<const float4*>(&h_s[r][k + 4]);
            acc[r] = fmaf(a0.x, w[0], fmaf(a0.y, w[1], fmaf(a0.z, w[2], fmaf(a0.w, w[3], acc[r]))));
            acc[r] = fmaf(a1.x, w[4], fmaf(a1.y, w[5], fmaf(a1.z, w[6], fmaf(a1.w, w[7], acc[r]))));
        }
    }
#pragma unroll
    for (int r = 0; r < 4; r++) part[wv][r][lane] = acc[r];
    __syncthreads();

    float xv = part[0][wv][lane] + part[1][wv][lane]
             + part[2][wv][lane] + part[3][wv][lane];
    const int onode = blockIdx.x * 4 + wv;
    x_out[(size_t)onode * DH + lane] = xv;
#pragma unroll
    for (int hh = 0; hh < PROJ_H; hh++) {
        float vl = xv * al[lane * PROJ_H + hh];
        float vr = xv * ar[lane * PROJ_H + hh];
#pragma unroll
        for (int off = 32; off >= 1; off >>= 1) {
            vl += __shfl_xor(vl, off, 64);
            vr += __shfl_xor(vr, off, 64);
        }
        if (lane == 0) {
            el_out[onode * PROJ_H + hh] = vl;
            er_out[onode * PROJ_H + hh] = vr;
        }
    }
}

// ---------------------------------------------------------------------------
// Kernel 4: final aggregate (H=1, no activation) -> d_out.
// ---------------------------------------------------------------------------
__global__ __launch_bounds__(256) void k_agg_final(
    const float* __restrict__ x_in, const float* __restrict__ el_in,
    const float* __restrict__ er_in, const int* __restrict__ nbr,
    const int* __restrict__ deg, const float* __restrict__ bias,
    float* __restrict__ out)
{
    const int node = blockIdx.x * 4 + (threadIdx.x >> 6);
    const int lane = threadIdx.x & 63;
    const float eli = el_in[node];
    float acc = 0.f, denp = 0.f;
    const int dg = deg[node];
    const int* nb = nbr + (size_t)node * CAP;

    for (int c0 = 0; c0 < dg; c0 += 64) {
        int jj = c0 + lane;
        int jidx = jj < dg ? jj : dg - 1;
        int j = nb[jidx];
        float e = er_in[j];
        float s = eli + e;
        s = s > 0.f ? s : 0.2f * s;
        float w = (jj < dg) ? __expf(s) : 0.f;
        denp += w;
        int cnt = dg - c0; cnt = cnt < 64 ? cnt : 64;
#pragma unroll 4
        for (int k = 0; k < cnt; k++) {
            int jk = __shfl(j, k, 64);
            float wk = __shfl(w, k, 64);
            float xv = x_in[(size_t)jk * DH + lane];
            acc = fmaf(wk, xv, acc);
        }
    }
#pragma unroll
    for (int off = 32; off >= 1; off >>= 1) denp += __shfl_xor(denp, off, 64);
    out[(size_t)node * DH + lane] = acc / fmaxf(denp, 1e-12f) + bias[lane];
}

// ---------------------------------------------------------------------------
extern "C" void kernel_launch(void* const* d_in, const int* in_sizes, int n_in,
                              void* d_out, int out_size, void* d_ws, size_t ws_size,
                              hipStream_t stream)
{
    const float* adj  = (const float*)d_in[0];
    const float* feat = (const float*)d_in[1];
    const float* W0   = (const float*)d_in[2];
    const float* al0  = (const float*)d_in[3];
    const float* ar0  = (const float*)d_in[4];
    const float* b0   = (const float*)d_in[5];
    const float* W1   = (const float*)d_in[6];
    const float* al1  = (const float*)d_in[7];
    const float* ar1  = (const float*)d_in[8];
    const float* b1   = (const float*)d_in[9];
    const float* W2   = (const float*)d_in[10];
    const float* al2  = (const float*)d_in[11];
    const float* ar2  = (const float*)d_in[12];
    const float* b2   = (const float*)d_in[13];
    float* out = (float*)d_out;

    char* ws = (char*)d_ws;
    int*   nbr = (int*)ws;   ws += (size_t)NNODES * CAP * sizeof(int);   // 2 MB
    int*   deg = (int*)ws;   ws += (size_t)NNODES * sizeof(int);         // 16 KB
    float* x0  = (float*)ws; ws += (size_t)NNODES * DH * sizeof(float);  // 1 MB
    float* x1  = (float*)ws; ws += (size_t)NNODES * DH * sizeof(float);  // 1 MB
    float* elA = (float*)ws; ws += (size_t)NNODES * 8 * sizeof(float);   // 128 KB
    float* erA = (float*)ws; ws += (size_t)NNODES * 8 * sizeof(float);   // 128 KB
    float* elB = (float*)ws; ws += (size_t)NNODES * 8 * sizeof(float);   // 128 KB
    float* erB = (float*)ws; ws += (size_t)NNODES * 8 * sizeof(float);   // 128 KB

    // K1: layer-0 mm/proj (blocks 0..1023, first) + build (4096 blocks)
    k_mm0_build<<<NNODES / 4 + NNODES, 256, 0, stream>>>(
        adj, nbr, deg, feat, W0, al0, ar0, x0, elA, erA);

    // K2: agg0 + mm1/proj1   (x0,elA,erA -> x1,elB,erB)
    k_agg_mm<8><<<NNODES / 4, 256, 0, stream>>>(
        x0, elA, erA, nbr, deg, b0, W1, al1, ar1, x1, elB, erB);

    // K3: agg1 + mm2/proj2   (x1,elB,erB -> x0,elA,erA; PROJ_H=1)
    k_agg_mm<1><<<NNODES / 4, 256, 0, stream>>>(
        x1, elB, erB, nbr, deg, b1, W2, al2, ar2, x0, elA, erA);

    // K4: final aggregate (H=1, no act) -> out
    k_agg_final<<<NNODES / 4, 256, 0, stream>>>(x0, elA, erA, nbr, deg, b2, out);
}